// Round 9
// baseline (526.450 us; speedup 1.0000x reference)
//
#include <hip/hip_runtime.h>
#include <hip/hip_bf16.h>
#include <hip/hip_cooperative_groups.h>

namespace cg = cooperative_groups;

// Problem constants
static constexpr int kB   = 8;
static constexpr int kP   = 196;
static constexpr int kL   = 80;
static constexpr int kD1  = 2048;
static constexpr int kD2  = 300;
static constexpr int kD2p = 320;       // p2 K padded to multiple of 64
static constexpr int kATT = 1024;
static constexpr int kM   = kB * kP;   // 1568 rows of p1
static constexpr int kR2  = kB * kL;   // 640 rows of p2
static constexpr int kOut = kB * kL * kP;        // 125440 outputs
static constexpr int kASplit = 16;     // alpha: a-dim split
static constexpr int kAChunk = kATT / kASplit;   // 64
static constexpr int kLPer   = 5;      // l per thread (16 groups x 5 = 80)
static constexpr int kAlphaTiles = 13 * kB * kASplit;  // 1664
static constexpr int kGrid = 1024;     // physical blocks (4/CU co-resident)

static constexpr float kTanhScale = 2.8853900817779268f;  // 2*log2(e)

static constexpr int kP2Blocks = (kR2 / 64) * (kATT / 64);       // 160
static constexpr int kP1Blocks = ((kM + 63) / 64) * (kATT / 64); // 400
static constexpr int kGemmBlocks = kP2Blocks + kP1Blocks;        // 560

// cast domain sizes (P0)
static constexpr int kD0i = kM * kD1 / 4;      // x1 float4s
static constexpr int kD1i = kATT * kD1 / 4;    // W1 float4s
static constexpr int kD2i = kR2 * kD2p;        // x2b elems (padded)
static constexpr int kD3i = kATT * kD2p;       // W2b elems (padded)
static constexpr int kCastTotal = kD0i + kD1i + kD2i + kD3i;
static constexpr int kCastBlk0  = 17;          // blocks [0,16)=v, 16=beta

typedef __attribute__((ext_vector_type(8))) short  bf16x8;
typedef __attribute__((ext_vector_type(4))) float  f32x4;

__device__ __forceinline__ unsigned short f2bf(float x) {
    union { float f; unsigned int u; } c; c.f = x;
    unsigned int r = c.u + 0x7fffu + ((c.u >> 16) & 1u);
    return (unsigned short)(r >> 16);
}

__device__ __forceinline__ void load_lds16(const void* g, void* l) {
    __builtin_amdgcn_global_load_lds(
        (const __attribute__((address_space(1))) void*)g,
        (__attribute__((address_space(3))) void*)l, 16, 0, 0);
}

// ---------------------------------------------------------------------------
// P0 bodies
// ---------------------------------------------------------------------------
__device__ __forceinline__ void cast_items(int bid, int tid,
        const float* __restrict__ x1, unsigned short* __restrict__ x1b,
        const float* __restrict__ W1, unsigned short* __restrict__ W1b,
        const float* __restrict__ x2, unsigned short* __restrict__ x2b,
        const float* __restrict__ W2, unsigned short* __restrict__ W2b,
        int nCastBlocks) {
    for (int i = bid * 256 + tid; i < kCastTotal; i += nCastBlocks * 256) {
        int j = i;
        if (j < kD0i) {
            float4 f = ((const float4*)x1)[j];
            ushort4 o = { f2bf(f.x), f2bf(f.y), f2bf(f.z), f2bf(f.w) };
            ((ushort4*)x1b)[j] = o;
        } else if ((j -= kD0i) < kD1i) {
            float4 f = ((const float4*)W1)[j];
            ushort4 o = { f2bf(f.x), f2bf(f.y), f2bf(f.z), f2bf(f.w) };
            ((ushort4*)W1b)[j] = o;
        } else if ((j -= kD1i) < kD2i) {
            int r = j / kD2p, c = j - r * kD2p;
            x2b[j] = (c < kD2) ? f2bf(x2[(size_t)r * kD2 + c]) : (unsigned short)0;
        } else {
            j -= kD2i;
            int r = j / kD2p, c = j - r * kD2p;
            W2b[j] = (c < kD2) ? f2bf(W2[(size_t)r * kD2 + c]) : (unsigned short)0;
        }
    }
}

// block bid in [0,16): v[bid*64 .. +64) = Wh^T wt  (atomic-free)
__device__ __forceinline__ void v_block(int bid, int tid,
        const float* __restrict__ Wh, const float* __restrict__ wt,
        float* __restrict__ v, float* vr /* LDS 4*64 floats */) {
    const int a  = bid * 64 + (tid & 63);
    const int cq = tid >> 6;                 // 0..3
    float acc = 0.0f;
    #pragma unroll 8
    for (int c = cq * 256; c < cq * 256 + 256; ++c)
        acc = fmaf(wt[c], Wh[(size_t)c * kATT + a], acc);
    vr[cq * 64 + (tid & 63)] = acc;
    __syncthreads();
    if (tid < 64)
        v[bid * 64 + tid] = vr[tid] + vr[64 + tid] + vr[128 + tid] + vr[192 + tid];
}

// block 16: beta = dot(wt,bh) + bt  (atomic-free, single wave)
__device__ __forceinline__ void beta_block(int tid,
        const float* __restrict__ wt, const float* __restrict__ bh,
        const float* __restrict__ bt, float* __restrict__ beta) {
    if (tid < 64) {
        float pb = 0.0f;
        #pragma unroll
        for (int j = 0; j < 16; ++j)
            pb = fmaf(wt[tid + 64 * j], bh[tid + 64 * j], pb);
        #pragma unroll
        for (int off = 32; off > 0; off >>= 1)
            pb += __shfl_down(pb, off, 64);
        if (tid == 0) beta[0] = pb + bt[0];
    }
}

// ---------------------------------------------------------------------------
// GEMM tile: C = scale * A·B^T, bf16 inputs, 64x64 tile, BK=64,
// global_load_lds staging (conflict-free), 4 waves, 2x2 MFMA 16x16x32.
// ---------------------------------------------------------------------------
__device__ __forceinline__ void gemm_tile(
        const unsigned short* __restrict__ Ab, const unsigned short* __restrict__ Bb,
        float* __restrict__ Co, int M, int K, float scale, int mx, int nx,
        unsigned short* As, unsigned short* Bs, int tid) {
    const int m0   = mx * 64;
    const int n0   = nx * 64;
    const int lane = tid & 63;
    const int wv   = tid >> 6;
    const int mh   = (wv >> 1) * 32;
    const int nh   = (wv & 1) * 32;
    const int row0 = tid >> 3,         ko = (tid & 7) * 8;
    const int row1 = (tid + 256) >> 3;
    const int ar0 = min(m0 + row0, M - 1), ar1 = min(m0 + row1, M - 1);
    const int br0 = n0 + row0,             br1 = n0 + row1;

    f32x4 acc[2][2] = {};
    for (int k0 = 0; k0 < K; k0 += 64) {
        load_lds16(Ab + (size_t)ar0 * K + k0 + ko, (char*)As + tid * 16);
        load_lds16(Ab + (size_t)ar1 * K + k0 + ko, (char*)As + (tid + 256) * 16);
        load_lds16(Bb + (size_t)br0 * K + k0 + ko, (char*)Bs + tid * 16);
        load_lds16(Bb + (size_t)br1 * K + k0 + ko, (char*)Bs + (tid + 256) * 16);
        __syncthreads();                      // drain loads, tiles visible
        #pragma unroll
        for (int kk = 0; kk < 2; ++kk) {
            bf16x8 af[2], bf[2];
            #pragma unroll
            for (int i = 0; i < 2; ++i) {
                int r = mh + i * 16 + (lane & 15);
                af[i] = *(const bf16x8*)((const char*)As + r * 128 + kk * 64 + (lane >> 4) * 16);
            }
            #pragma unroll
            for (int j = 0; j < 2; ++j) {
                int r = nh + j * 16 + (lane & 15);
                bf[j] = *(const bf16x8*)((const char*)Bs + r * 128 + kk * 64 + (lane >> 4) * 16);
            }
            #pragma unroll
            for (int i = 0; i < 2; ++i)
                #pragma unroll
                for (int j = 0; j < 2; ++j)
                    acc[i][j] = __builtin_amdgcn_mfma_f32_16x16x32_bf16(
                                    af[i], bf[j], acc[i][j], 0, 0, 0);
        }
        __syncthreads();                      // reads done before next stage
    }
    // C/D layout: col = lane&15, row = (lane>>4)*4 + reg   [m89/m91 verified]
    #pragma unroll
    for (int i = 0; i < 2; ++i)
        #pragma unroll
        for (int j = 0; j < 2; ++j)
            #pragma unroll
            for (int r = 0; r < 4; ++r) {
                int m = m0 + mh + i * 16 + (lane >> 4) * 4 + r;
                int n = n0 + nh + j * 16 + (lane & 15);
                if (m < M) Co[(size_t)m * kATT + n] = scale * acc[i][j][r];
            }
}

__device__ __forceinline__ void gemm_dispatch(int bid, int tid,
        const unsigned short* x1b, const unsigned short* W1b,
        const unsigned short* x2b, const unsigned short* W2b,
        float* p1w, float* p2w, unsigned short* As, unsigned short* Bs) {
    if (bid < kP2Blocks) {
        gemm_tile(x2b, W2b, p2w, kR2, kD2p, 1.0f,
                  bid % (kR2 / 64), bid / (kR2 / 64), As, Bs, tid);
    } else {
        int l = bid - kP2Blocks;
        gemm_tile(x1b, W1b, p1w, kM, kD1, kTanhScale,
                  l % ((kM + 63) / 64), l / ((kM + 63) / 64), As, Bs, tid);
    }
}

// ---------------------------------------------------------------------------
// alpha tile (one of 1664): p1 pre-scaled by 2log2e;
//   sum_a v*tanh = sumV - 2*sum_a v*rcp(exp2(u*w)+1)
// ---------------------------------------------------------------------------
__device__ __forceinline__ void alpha_tile(int vb, int tid,
        const float* __restrict__ p1, const float* __restrict__ p2,
        const float* __restrict__ v, float* __restrict__ part,
        float* vs /*64 floats LDS*/, float* sredp /*1 float LDS*/) {
    const int px = vb % 13;
    const int b  = (vb / 13) & (kB - 1);
    const int as = vb / (13 * kB);
    const int aBase = as * kAChunk;
    const int p0 = px * 16;
    const int tp = tid & 15;
    const int lg = tid >> 4;

    if (tid < kAChunk) vs[tid] = v[aBase + tid];
    __syncthreads();
    if (tid < 64) {
        float s = vs[tid];
        #pragma unroll
        for (int off = 32; off > 0; off >>= 1)
            s += __shfl_down(s, off, 64);
        if (tid == 0) *sredp = s;
    }
    __syncthreads();
    const float sumV = *sredp;

    const int p   = p0 + tp;
    const int gr1 = b * kP + min(p, kP - 1);
    const float* pu = p1 + (size_t)gr1 * kATT + aBase;
    const float* pw = p2 + ((size_t)(b * kL + lg * kLPer)) * kATT + aBase;

    float acc[kLPer] = {};
    #pragma unroll 2
    for (int a4 = 0; a4 < kAChunk / 4; ++a4) {
        float4 u  = *(const float4*)(pu + a4 * 4);
        float4 vv = *(const float4*)&vs[a4 * 4];
        #pragma unroll
        for (int j = 0; j < kLPer; ++j) {
            float4 w = *(const float4*)(pw + (size_t)j * kATT + a4 * 4);
            acc[j] = fmaf(vv.x, __builtin_amdgcn_rcpf(__builtin_amdgcn_exp2f(u.x * w.x) + 1.0f), acc[j]);
            acc[j] = fmaf(vv.y, __builtin_amdgcn_rcpf(__builtin_amdgcn_exp2f(u.y * w.y) + 1.0f), acc[j]);
            acc[j] = fmaf(vv.z, __builtin_amdgcn_rcpf(__builtin_amdgcn_exp2f(u.z * w.z) + 1.0f), acc[j]);
            acc[j] = fmaf(vv.w, __builtin_amdgcn_rcpf(__builtin_amdgcn_exp2f(u.w * w.w) + 1.0f), acc[j]);
        }
    }
    if (p < kP) {
        float* po = part + (size_t)as * kOut + ((size_t)b * kL + lg * kLPer) * kP + p;
        #pragma unroll
        for (int j = 0; j < kLPer; ++j)
            po[(size_t)j * kP] = sumV - 2.0f * acc[j];
    }
}

// ---------------------------------------------------------------------------
// Fused cooperative kernel: P0 cast + v/beta | P1 GEMMs | P2 alpha | P3 reduce
// ---------------------------------------------------------------------------
__global__ __launch_bounds__(256, 4) void fused_kernel(
        const float* __restrict__ x1, const float* __restrict__ x2,
        const float* __restrict__ W1, const float* __restrict__ W2,
        const float* __restrict__ Wh, const float* __restrict__ bh,
        const float* __restrict__ wt, const float* __restrict__ bt,
        float* p2w, float* p1w, float* v, float* beta, float* part, float* out,
        unsigned short* x1b, unsigned short* W1b,
        unsigned short* x2b, unsigned short* W2b) {
    __shared__ __align__(16) unsigned char smem[16384];
    unsigned short* As = (unsigned short*)smem;
    unsigned short* Bs = (unsigned short*)(smem + 8192);
    float* vr    = (float*)smem;           // P0: 4*64 floats
    float* vs    = (float*)smem;           // P2: 64 floats
    float* sredp = (float*)(smem + 256);   // P2: 1 float

    const int bid = blockIdx.x;
    const int tid = threadIdx.x;
    cg::grid_group grid = cg::this_grid();

    // -------- P0: casts + v + beta --------
    if (bid < 16)            v_block(bid, tid, Wh, wt, v, vr);
    else if (bid == 16)      beta_block(tid, wt, bh, bt, beta);
    else                     cast_items(bid - kCastBlk0, tid, x1, x1b, W1, W1b,
                                        x2, x2b, W2, W2b, kGrid - kCastBlk0);
    grid.sync();

    // -------- P1: GEMMs --------
    if (bid < kGemmBlocks)
        gemm_dispatch(bid, tid, x1b, W1b, x2b, W2b, p1w, p2w, As, Bs);
    grid.sync();

    // -------- P2: alpha (1664 virtual tiles) --------
    for (int vb = bid; vb < kAlphaTiles; vb += kGrid) {
        alpha_tile(vb, tid, p1w, p2w, v, part, vs, sredp);
        __syncthreads();                   // vs reuse guard
    }
    grid.sync();

    // -------- P3: reduce --------
    {
        int i = bid * 256 + tid;
        if (i < kOut) {
            float s = beta[0];
            #pragma unroll
            for (int r = 0; r < kASplit; ++r)
                s += part[(size_t)r * kOut + i];
            out[i] = s;
        }
    }
}

// ---------------------------------------------------------------------------
// Fallback (non-cooperative) kernels — same bodies, separate launches
// ---------------------------------------------------------------------------
__global__ __launch_bounds__(256) void prep_fb(
        const float* __restrict__ x1, const float* __restrict__ x2,
        const float* __restrict__ W1, const float* __restrict__ W2,
        const float* __restrict__ Wh, const float* __restrict__ bh,
        const float* __restrict__ wt, const float* __restrict__ bt,
        float* v, float* beta,
        unsigned short* x1b, unsigned short* W1b,
        unsigned short* x2b, unsigned short* W2b) {
    __shared__ float vr[256];
    const int bid = blockIdx.x, tid = threadIdx.x;
    if (bid < 16)       v_block(bid, tid, Wh, wt, v, vr);
    else if (bid == 16) beta_block(tid, wt, bh, bt, beta);
    else                cast_items(bid - kCastBlk0, tid, x1, x1b, W1, W1b,
                                   x2, x2b, W2, W2b, kGrid - kCastBlk0);
}

__global__ __launch_bounds__(256) void gemm_fb(
        const unsigned short* x1b, const unsigned short* W1b,
        const unsigned short* x2b, const unsigned short* W2b,
        float* p1w, float* p2w) {
    __shared__ __align__(16) unsigned char smem[16384];
    gemm_dispatch(blockIdx.x, threadIdx.x, x1b, W1b, x2b, W2b, p1w, p2w,
                  (unsigned short*)smem, (unsigned short*)(smem + 8192));
}

__global__ __launch_bounds__(256) void alpha_fb(
        const float* __restrict__ p1, const float* __restrict__ p2,
        const float* __restrict__ v, float* __restrict__ part) {
    __shared__ float vs[64];
    __shared__ float sred;
    alpha_tile(blockIdx.x, threadIdx.x, p1, p2, v, part, vs, &sred);
}

__global__ __launch_bounds__(256) void reduce_fb(
        const float* __restrict__ part, const float* __restrict__ beta,
        float* __restrict__ out) {
    int i = blockIdx.x * 256 + threadIdx.x;
    if (i < kOut) {
        float s = beta[0];
        #pragma unroll
        for (int r = 0; r < kASplit; ++r)
            s += part[(size_t)r * kOut + i];
        out[i] = s;
    }
}

// ---------------------------------------------------------------------------
extern "C" void kernel_launch(void* const* d_in, const int* in_sizes, int n_in,
                              void* d_out, int out_size, void* d_ws, size_t ws_size,
                              hipStream_t stream) {
    const float* x1 = (const float*)d_in[0];
    const float* x2 = (const float*)d_in[1];
    const float* W1 = (const float*)d_in[2];
    const float* W2 = (const float*)d_in[3];
    const float* Wh = (const float*)d_in[4];
    const float* bh = (const float*)d_in[5];
    const float* wt = (const float*)d_in[6];
    const float* bt = (const float*)d_in[7];
    float* out = (float*)d_out;

    // ws: v[1024] | beta pad->1088 | p2w | p1w | part | bf16{x1b,W1b,x2b,W2b}
    float* ws   = (float*)d_ws;
    float* v    = ws;
    float* beta = ws + 1024;
    float* p2w  = ws + 1088;
    float* p1w  = p2w + (size_t)kR2 * kATT;
    float* part = p1w + (size_t)kM * kATT;
    unsigned short* x1b = (unsigned short*)(part + (size_t)kASplit * kOut);
    unsigned short* W1b = x1b + (size_t)kM * kD1;
    unsigned short* x2b = W1b + (size_t)kATT * kD1;
    unsigned short* W2b = x2b + (size_t)kR2 * kD2p;

    void* args[] = { (void*)&x1, (void*)&x2, (void*)&W1, (void*)&W2,
                     (void*)&Wh, (void*)&bh, (void*)&wt, (void*)&bt,
                     (void*)&p2w, (void*)&p1w, (void*)&v, (void*)&beta,
                     (void*)&part, (void*)&out,
                     (void*)&x1b, (void*)&W1b, (void*)&x2b, (void*)&W2b };
    hipError_t rc = hipLaunchCooperativeKernel(
        (void*)fused_kernel, dim3(kGrid), dim3(256), args, 0, stream);

    if (rc != hipSuccess) {   // stable fallback: separate launches
        prep_fb<<<dim3(kGrid), 256, 0, stream>>>(
            x1, x2, W1, W2, Wh, bh, wt, bt, v, beta, x1b, W1b, x2b, W2b);
        gemm_fb<<<dim3(kGemmBlocks), 256, 0, stream>>>(
            x1b, W1b, x2b, W2b, p1w, p2w);
        alpha_fb<<<dim3(kAlphaTiles), 256, 0, stream>>>(p1w, p2w, v, part);
        reduce_fb<<<dim3((kOut + 255) / 256), 256, 0, stream>>>(part, beta, out);
    }
}

// Round 10
// 161.671 us; speedup vs baseline: 3.2563x; 3.2563x over previous
//
#include <hip/hip_runtime.h>
#include <hip/hip_bf16.h>

// Problem constants
static constexpr int kB   = 8;
static constexpr int kP   = 196;
static constexpr int kL   = 80;
static constexpr int kD1  = 2048;
static constexpr int kD2  = 300;
static constexpr int kD2p = 320;       // p2 K padded to multiple of 64
static constexpr int kATT = 1024;
static constexpr int kM   = kB * kP;   // 1568 rows of p1
static constexpr int kR2  = kB * kL;   // 640 rows of p2
static constexpr int kOut = kB * kL * kP;        // 125440 outputs
static constexpr int kASplit = 16;     // alpha: a-dim split across blocks
static constexpr int kAChunk = kATT / kASplit;   // 64
static constexpr int kLPer   = 5;      // l per thread (16 groups x 5 = 80)

static constexpr float kTanhScale = 2.8853900817779268f;  // 2*log2(e)

typedef __attribute__((ext_vector_type(8))) short  bf16x8;
typedef __attribute__((ext_vector_type(4))) float  f32x4;

__device__ __forceinline__ unsigned short f2bf(float x) {
    union { float f; unsigned int u; } c; c.f = x;
    unsigned int r = c.u + 0x7fffu + ((c.u >> 16) & 1u);
    return (unsigned short)(r >> 16);
}

__device__ __forceinline__ void load_lds16(const void* g, void* l) {
    __builtin_amdgcn_global_load_lds(
        (const __attribute__((address_space(1))) void*)g,
        (__attribute__((address_space(3))) void*)l, 16, 0, 0);
}

// ---------------------------------------------------------------------------
// prep: blocks [0,16) -> v (atomic-free), block 16 -> beta, rest -> casts.
// ---------------------------------------------------------------------------
static constexpr int kD0i = kM * kD1 / 4;      // x1 float4s
static constexpr int kD1i = kATT * kD1 / 4;    // W1 float4s
static constexpr int kD2i = kR2 * kD2p;        // x2b elems (padded)
static constexpr int kD3i = kATT * kD2p;       // W2b elems (padded)
static constexpr int kCastTotal  = kD0i + kD1i + kD2i + kD3i;
static constexpr int kCastBlocks = (kCastTotal + 255) / 256;   // 7264
static constexpr int kPrepBlocks = 17 + kCastBlocks;

__global__ __launch_bounds__(256) void prep_kernel(
        const float* __restrict__ x1, unsigned short* __restrict__ x1b,
        const float* __restrict__ W1, unsigned short* __restrict__ W1b,
        const float* __restrict__ x2, unsigned short* __restrict__ x2b,
        const float* __restrict__ W2, unsigned short* __restrict__ W2b,
        const float* __restrict__ Wh, const float* __restrict__ wt,
        const float* __restrict__ bh, const float* __restrict__ bt,
        float* __restrict__ v, float* __restrict__ beta) {
    __shared__ float vr[256];
    const int bid = blockIdx.x, tid = threadIdx.x;
    if (bid < 16) {                        // ---- v[bid*64 .. +64) atomic-free
        const int a  = bid * 64 + (tid & 63);
        const int cq = tid >> 6;           // 0..3: c-quarter
        float acc = 0.0f;
        #pragma unroll 8
        for (int c = cq * 256; c < cq * 256 + 256; ++c)
            acc = fmaf(wt[c], Wh[(size_t)c * kATT + a], acc);
        vr[cq * 64 + (tid & 63)] = acc;
        __syncthreads();
        if (tid < 64)
            v[bid * 64 + tid] = vr[tid] + vr[64 + tid] + vr[128 + tid] + vr[192 + tid];
        return;
    }
    if (bid == 16) {                       // ---- beta = dot(wt,bh) + bt
        if (tid < 64) {
            float pb = 0.0f;
            #pragma unroll
            for (int j = 0; j < 16; ++j)
                pb = fmaf(wt[tid + 64 * j], bh[tid + 64 * j], pb);
            #pragma unroll
            for (int off = 32; off > 0; off >>= 1)
                pb += __shfl_down(pb, off, 64);
            if (tid == 0) beta[0] = pb + bt[0];
        }
        return;
    }
    int i = (bid - 17) * 256 + tid;        // ---- casts
    if (i < kD0i) {
        float4 f = ((const float4*)x1)[i];
        ushort4 o = { f2bf(f.x), f2bf(f.y), f2bf(f.z), f2bf(f.w) };
        ((ushort4*)x1b)[i] = o;
    } else if ((i -= kD0i) < kD1i) {
        float4 f = ((const float4*)W1)[i];
        ushort4 o = { f2bf(f.x), f2bf(f.y), f2bf(f.z), f2bf(f.w) };
        ((ushort4*)W1b)[i] = o;
    } else if ((i -= kD1i) < kD2i) {
        int r = i / kD2p, c = i - r * kD2p;
        x2b[i] = (c < kD2) ? f2bf(x2[(size_t)r * kD2 + c]) : (unsigned short)0;
    } else if ((i -= kD2i) < kD3i) {
        int r = i / kD2p, c = i - r * kD2p;
        W2b[i] = (c < kD2) ? f2bf(W2[(size_t)r * kD2 + c]) : (unsigned short)0;
    }
}

// ---------------------------------------------------------------------------
// Fused GEMMs: [0,160) p2 (M=640,K=320) | [160,560) p1 (M=1568,K=2048,
// scale=2log2e). 64x64 tile, BK=64, global_load_lds staging, XOR-swizzled
// LDS layout: row r chunk j (16B) lives at slot j^(r&7) -> ds_read_b128
// spreads over all 32 banks (2-way alias only, free per m136).
// ---------------------------------------------------------------------------
static constexpr int kP2Blocks = (kR2 / 64) * (kATT / 64);       // 160
static constexpr int kP1Blocks = ((kM + 63) / 64) * (kATT / 64); // 400

__global__ __launch_bounds__(256) void gemm_all_kernel(
        const unsigned short* __restrict__ x2b, const unsigned short* __restrict__ W2b,
        float* __restrict__ p2w,
        const unsigned short* __restrict__ x1b, const unsigned short* __restrict__ W1b,
        float* __restrict__ p1w) {
    __shared__ unsigned short As[64 * 64];   // 8 KB
    __shared__ unsigned short Bs[64 * 64];   // 8 KB

    const unsigned short *Ab, *Bb;
    float* Co; int M, K, mx, nx; float scale;
    {
        int bid = blockIdx.x;
        if (bid < kP2Blocks) {
            Ab = x2b; Bb = W2b; Co = p2w; M = kR2; K = kD2p; scale = 1.0f;
            mx = bid % (kR2 / 64); nx = bid / (kR2 / 64);
        } else {
            int l = bid - kP2Blocks;
            Ab = x1b; Bb = W1b; Co = p1w; M = kM; K = kD1; scale = kTanhScale;
            mx = l % ((kM + 63) / 64); nx = l / ((kM + 63) / 64);
        }
    }
    const int m0   = mx * 64;
    const int n0   = nx * 64;
    const int tid  = threadIdx.x;
    const int lane = tid & 63;
    const int wv   = tid >> 6;
    const int mh   = (wv >> 1) * 32;
    const int nh   = (wv & 1) * 32;

    // staging: thread stages rows tid>>3 and (tid>>3)+32; source chunk index
    // XOR-swizzled so LDS slot s of row r holds global chunk s^(r&7).
    const int srow = tid >> 3;
    const int ko   = (((tid & 7) ^ (srow & 7))) * 8;   // elems; same for row+32
    const int ar0 = min(m0 + srow, M - 1), ar1 = min(m0 + srow + 32, M - 1);
    const int br0 = n0 + srow,             br1 = n0 + srow + 32;

    f32x4 acc[2][2] = {};
    for (int k0 = 0; k0 < K; k0 += 64) {
        load_lds16(Ab + (size_t)ar0 * K + k0 + ko, (char*)As + tid * 16);
        load_lds16(Ab + (size_t)ar1 * K + k0 + ko, (char*)As + (tid + 256) * 16);
        load_lds16(Bb + (size_t)br0 * K + k0 + ko, (char*)Bs + tid * 16);
        load_lds16(Bb + (size_t)br1 * K + k0 + ko, (char*)Bs + (tid + 256) * 16);
        __syncthreads();                      // drain loads, tiles visible
        #pragma unroll
        for (int kk = 0; kk < 2; ++kk) {
            bf16x8 af[2], bf[2];
            #pragma unroll
            for (int i = 0; i < 2; ++i) {
                int r = mh + i * 16 + (lane & 15);
                int s = (kk * 4 + (lane >> 4)) ^ (r & 7);   // swizzled slot
                af[i] = *(const bf16x8*)((const char*)As + r * 128 + s * 16);
            }
            #pragma unroll
            for (int j = 0; j < 2; ++j) {
                int r = nh + j * 16 + (lane & 15);
                int s = (kk * 4 + (lane >> 4)) ^ (r & 7);
                bf[j] = *(const bf16x8*)((const char*)Bs + r * 128 + s * 16);
            }
            #pragma unroll
            for (int i = 0; i < 2; ++i)
                #pragma unroll
                for (int j = 0; j < 2; ++j)
                    acc[i][j] = __builtin_amdgcn_mfma_f32_16x16x32_bf16(
                                    af[i], bf[j], acc[i][j], 0, 0, 0);
        }
        __syncthreads();                      // reads done before next stage
    }

    // C/D layout: col = lane&15, row = (lane>>4)*4 + reg   [m89/m91 verified]
    #pragma unroll
    for (int i = 0; i < 2; ++i)
        #pragma unroll
        for (int j = 0; j < 2; ++j)
            #pragma unroll
            for (int r = 0; r < 4; ++r) {
                int m = m0 + mh + i * 16 + (lane >> 4) * 4 + r;
                int n = n0 + nh + j * 16 + (lane & 15);
                if (m < M) Co[(size_t)m * kATT + n] = scale * acc[i][j][r];
            }
}

// ---------------------------------------------------------------------------
// alpha partial, register-blocked streaming, atomic-free split-K.
//   p1 pre-scaled by 2log2(e): sum_a v*tanh = sumV - 2*sum_a v*rcp(exp2(u*w)+1)
// grid (13, kB, kASplit); block 256 = 16 p x 16 l-groups (5 l each).
// ---------------------------------------------------------------------------
__global__ __launch_bounds__(256) void alpha_kernel(
        const float* __restrict__ p1, const float* __restrict__ p2,
        const float* __restrict__ v, float* __restrict__ part) {
    __shared__ float vs[kAChunk];            // 256 B
    __shared__ float sred;
    const int b     = blockIdx.y;
    const int as    = blockIdx.z;
    const int aBase = as * kAChunk;
    const int p0    = blockIdx.x * 16;
    const int tid   = threadIdx.x;
    const int tp    = tid & 15;              // p lane -> 16-line u loads
    const int lg    = tid >> 4;              // l-group: l = lg*5 + j

    if (tid < kAChunk) vs[tid] = v[aBase + tid];
    __syncthreads();
    if (tid < 64) {                          // sumV of chunk (kAChunk == 64)
        float s = vs[tid];
        #pragma unroll
        for (int off = 32; off > 0; off >>= 1)
            s += __shfl_down(s, off, 64);
        if (tid == 0) sred = s;
    }
    __syncthreads();
    const float sumV = sred;

    const int p   = p0 + tp;
    const int gr1 = b * kP + min(p, kP - 1);
    const float* pu = p1 + (size_t)gr1 * kATT + aBase;
    const float* pw = p2 + ((size_t)(b * kL + lg * kLPer)) * kATT + aBase;

    float acc[kLPer] = {};
    #pragma unroll 2
    for (int a4 = 0; a4 < kAChunk / 4; ++a4) {
        float4 u  = *(const float4*)(pu + a4 * 4);
        float4 vv = *(const float4*)&vs[a4 * 4];
        #pragma unroll
        for (int j = 0; j < kLPer; ++j) {
            float4 w = *(const float4*)(pw + (size_t)j * kATT + a4 * 4);
            acc[j] = fmaf(vv.x, __builtin_amdgcn_rcpf(__builtin_amdgcn_exp2f(u.x * w.x) + 1.0f), acc[j]);
            acc[j] = fmaf(vv.y, __builtin_amdgcn_rcpf(__builtin_amdgcn_exp2f(u.y * w.y) + 1.0f), acc[j]);
            acc[j] = fmaf(vv.z, __builtin_amdgcn_rcpf(__builtin_amdgcn_exp2f(u.z * w.z) + 1.0f), acc[j]);
            acc[j] = fmaf(vv.w, __builtin_amdgcn_rcpf(__builtin_amdgcn_exp2f(u.w * w.w) + 1.0f), acc[j]);
        }
    }
    if (p < kP) {
        float* po = part + (size_t)as * kOut + ((size_t)b * kL + lg * kLPer) * kP + p;
        #pragma unroll
        for (int j = 0; j < kLPer; ++j)
            po[(size_t)j * kP] = sumV - 2.0f * acc[j];
    }
}

// ---------------------------------------------------------------------------
// out[i] = beta + sum_s part[s][i]
// ---------------------------------------------------------------------------
__global__ __launch_bounds__(256) void reduce_kernel(
        const float* __restrict__ part, const float* __restrict__ beta,
        float* __restrict__ out) {
    int i = blockIdx.x * 256 + threadIdx.x;
    if (i < kOut) {
        float s = beta[0];
        #pragma unroll
        for (int r = 0; r < kASplit; ++r)
            s += part[(size_t)r * kOut + i];
        out[i] = s;
    }
}

// ---------------------------------------------------------------------------
extern "C" void kernel_launch(void* const* d_in, const int* in_sizes, int n_in,
                              void* d_out, int out_size, void* d_ws, size_t ws_size,
                              hipStream_t stream) {
    const float* x1 = (const float*)d_in[0];
    const float* x2 = (const float*)d_in[1];
    const float* W1 = (const float*)d_in[2];
    const float* W2 = (const float*)d_in[3];
    const float* Wh = (const float*)d_in[4];
    const float* bh = (const float*)d_in[5];
    const float* wt = (const float*)d_in[6];
    const float* bt = (const float*)d_in[7];
    float* out = (float*)d_out;

    // ws: v[1024] | beta pad->1088 | p2w | p1w | part | bf16{x1b,W1b,x2b,W2b}
    float* ws   = (float*)d_ws;
    float* v    = ws;
    float* beta = ws + 1024;
    float* p2w  = ws + 1088;
    float* p1w  = p2w + (size_t)kR2 * kATT;
    float* part = p1w + (size_t)kM * kATT;
    unsigned short* x1b = (unsigned short*)(part + (size_t)kASplit * kOut);
    unsigned short* W1b = x1b + (size_t)kM * kD1;
    unsigned short* x2b = W1b + (size_t)kATT * kD1;
    unsigned short* W2b = x2b + (size_t)kR2 * kD2p;

    prep_kernel<<<dim3(kPrepBlocks), 256, 0, stream>>>(
        x1, x1b, W1, W1b, x2, x2b, W2, W2b, Wh, wt, bh, bt, v, beta);
    gemm_all_kernel<<<dim3(kP2Blocks + kP1Blocks), 256, 0, stream>>>(
        x2b, W2b, p2w, x1b, W1b, p1w);
    alpha_kernel<<<dim3((kP + 15) / 16, kB, kASplit), 256, 0, stream>>>(
        p1w, p2w, v, part);
    reduce_kernel<<<dim3((kOut + 255) / 256), 256, 0, stream>>>(part, beta, out);
}